// Round 8
// baseline (97.071 us; speedup 1.0000x reference)
//
#include <hip/hip_runtime.h>
#include <hip/hip_bf16.h>

#define Bv 32
#define Cv 64
#define Nv 1024

typedef __attribute__((ext_vector_type(8))) short bf16x8;
typedef __attribute__((ext_vector_type(4))) float f32x4;
typedef __attribute__((ext_vector_type(8))) unsigned short us8;
typedef __attribute__((ext_vector_type(4))) unsigned short us4;

__device__ __forceinline__ float lrelu(float v) { return v >= 0.f ? v : 0.2f * v; }
__device__ __forceinline__ float sigmoidf_(float z) { return 1.f / (1.f + __expf(-z)); }
// HW bf16 convert (RTNE). Compiler emits v_cvt_pk_bf16_f32 for these casts.
__device__ __forceinline__ unsigned short f2b(float f) {
  __hip_bfloat16 h = __float2bfloat16(f);
  return reinterpret_cast<unsigned short&>(h);
}
__device__ __forceinline__ void gload16(const void* g, void* l) {
  __builtin_amdgcn_global_load_lds((const __attribute__((address_space(1))) void*)g,
                                   (__attribute__((address_space(3))) void*)l, 16, 0, 0);
}
// 64x64 bf16 tile, linear LDS dest, XOR-swizzled global source; granule g of
// row r holds global granule g ^ (r&7). fragr applies the same XOR on read.
__device__ __forceinline__ void stage_tile(const unsigned short* src, size_t stride,
                                           unsigned short* dst, int wave, int lane) {
#pragma unroll
  for (int p = 0; p < 2; ++p) {
    int q = wave * 2 + p;
    int rr = q * 8 + (lane >> 3);
    int gS = ((lane & 7) ^ (rr & 7)) << 3;
    gload16(&src[(size_t)rr * stride + gS], &dst[q * 512]);
  }
}
__device__ __forceinline__ bf16x8 fragr(const unsigned short* buf, int row, int ks, int lane) {
  return *reinterpret_cast<const bf16x8*>(
      &buf[row * 64 + (((ks * 4 + (lane >> 4)) ^ (row & 7)) << 3)]);
}

// ---------------------------------------------------------------------------
// prep: f32->bf16 conversions; x read once (straight + transposed).
// ---------------------------------------------------------------------------
__device__ __forceinline__ void cvt8(const float* in, unsigned short* out, int i) {
  const f32x4* p = reinterpret_cast<const f32x4*>(in + (size_t)i * 8);
  f32x4 a = p[0], b = p[1];
  us8 o;
  o[0] = f2b(a[0]); o[1] = f2b(a[1]); o[2] = f2b(a[2]); o[3] = f2b(a[3]);
  o[4] = f2b(b[0]); o[5] = f2b(b[1]); o[6] = f2b(b[2]); o[7] = f2b(b[3]);
  *reinterpret_cast<us8*>(out + (size_t)i * 8) = o;
}

__global__ __launch_bounds__(256)
void prep_kernel(const float* __restrict__ x, const float* __restrict__ Wsa,
                 const float* __restrict__ Wcm, const float* __restrict__ Wsw,
                 const float* __restrict__ Wdw, unsigned short* __restrict__ xb,
                 unsigned short* __restrict__ xbT, unsigned short* __restrict__ WsaB,
                 unsigned short* __restrict__ WcmB, unsigned short* __restrict__ WswB,
                 unsigned short* __restrict__ WdwB) {
  __shared__ unsigned short L[64 * 72];
  const int blk = blockIdx.x, tid = threadIdx.x;
  if (blk < 512) {
    int b = blk >> 4, n0 = (blk & 15) * 64;
    int c = tid >> 2, nseg = (tid & 3) * 16;
    const float* src = &x[((size_t)(b * 64 + c) << 10) + n0 + nseg];
#pragma unroll
    for (int q = 0; q < 4; ++q) {
      f32x4 v = *reinterpret_cast<const f32x4*>(src + q * 4);
      us4 w4;
#pragma unroll
      for (int e = 0; e < 4; ++e) {
        unsigned short bf = f2b(v[e]);
        L[(nseg + q * 4 + e) * 72 + c] = bf;
        w4[e] = bf;
      }
      *reinterpret_cast<us4*>(&xb[((size_t)(b * 64 + c) << 10) + n0 + nseg + q * 4]) = w4;
    }
    __syncthreads();
    int n = tid >> 2, cs = (tid & 3) * 16;
    us8 a = *reinterpret_cast<const us8*>(&L[n * 72 + cs]);
    us8 bq = *reinterpret_cast<const us8*>(&L[n * 72 + cs + 8]);
    unsigned short* dst = &xbT[(((size_t)b << 10) + n0 + n) * 64 + cs];
    *reinterpret_cast<us8*>(dst) = a;
    *reinterpret_cast<us8*>(dst + 8) = bq;
  } else if (blk < 1024) {
    cvt8(Wsa, WsaB, (blk - 512) * 256 + tid);
  } else if (blk < 1056) {
    cvt8(Wcm, WcmB, (blk - 1024) * 256 + tid);
  } else if (blk < 1058) {
    cvt8(Wsw, WswB, (blk - 1056) * 256 + tid);
  } else {
    cvt8(Wdw, WdwB, (blk - 1058) * 256 + tid);
  }
}

// ---------------------------------------------------------------------------
// k1x1: fused  t = lrelu(x @ Wsa^T)  ->  x1 = x + lrelu(Wsw @ t + bsw)
// 2-buffer double-buffered staging, FULLY UNROLLED K-loop (compile-time
// buffer slots -> all LDS addresses strength-reduced).
// Energy balanced: block x accumulates its own K-slab partial -> en_part[x][b].
// ---------------------------------------------------------------------------
__global__ __launch_bounds__(256)
void k1x1_kernel(const unsigned short* __restrict__ xb,
                 const unsigned short* __restrict__ WsaB,
                 const unsigned short* __restrict__ WswB,
                 const float* __restrict__ x, const float* __restrict__ bsw,
                 unsigned short* __restrict__ x1b, float* __restrict__ en_part) {
  __shared__ __align__(16) unsigned short As[2][4096];
  __shared__ __align__(16) unsigned short Bs[2][4096];
  __shared__ __align__(16) unsigned short TT[64 * 72];
  __shared__ __align__(16) float Xres[64 * 68];
  const int tid = threadIdx.x, wave = tid >> 6, lane = tid & 63;
  const int b = blockIdx.y, col0 = blockIdx.x * 64, row0 = b * 64;
  const int wr = wave >> 1, wc = wave & 1;
  f32x4 acc[2][2], accE[4];
#pragma unroll
  for (int i = 0; i < 2; ++i)
#pragma unroll
    for (int j = 0; j < 2; ++j) acc[i][j] = (f32x4){0.f, 0.f, 0.f, 0.f};
#pragma unroll
  for (int j = 0; j < 4; ++j) accE[j] = (f32x4){0.f, 0.f, 0.f, 0.f};

  stage_tile(&xb[(size_t)row0 * Nv], Nv, As[0], wave, lane);
  stage_tile(&WsaB[(size_t)col0 * Nv], Nv, Bs[0], wave, lane);
  __syncthreads();
#pragma unroll
  for (int t = 0; t < 16; ++t) {
    const int cur = t & 1;
    if (t < 15) {
      stage_tile(&xb[(size_t)row0 * Nv + (t + 1) * 64], Nv, As[cur ^ 1], wave, lane);
      stage_tile(&WsaB[(size_t)col0 * Nv + (t + 1) * 64], Nv, Bs[cur ^ 1], wave, lane);
    }
#pragma unroll
    for (int ks = 0; ks < 2; ++ks) {
      bf16x8 af[2], bfg[2];
#pragma unroll
      for (int i = 0; i < 2; ++i) af[i] = fragr(As[cur], wr * 32 + i * 16 + (lane & 15), ks, lane);
#pragma unroll
      for (int j = 0; j < 2; ++j) bfg[j] = fragr(Bs[cur], wc * 32 + j * 16 + (lane & 15), ks, lane);
#pragma unroll
      for (int i = 0; i < 2; ++i)
#pragma unroll
        for (int j = 0; j < 2; ++j)
          acc[i][j] = __builtin_amdgcn_mfma_f32_16x16x32_bf16(af[i], bfg[j], acc[i][j], 0, 0, 0);
    }
    if (t == blockIdx.x) {  // balanced energy partial
#pragma unroll
      for (int ks = 0; ks < 2; ++ks) {
        bf16x8 aE = fragr(As[cur], wave * 16 + (lane & 15), ks, lane);
#pragma unroll
        for (int j = 0; j < 4; ++j) {
          bf16x8 bE = fragr(As[cur], j * 16 + (lane & 15), ks, lane);
          accE[j] = __builtin_amdgcn_mfma_f32_16x16x32_bf16(aE, bE, accE[j], 0, 0, 0);
        }
      }
    }
    __syncthreads();
  }
  // t-tile -> TT [n][c]
#pragma unroll
  for (int i = 0; i < 2; ++i)
#pragma unroll
    for (int j = 0; j < 2; ++j) {
      us4 tv;
#pragma unroll
      for (int r = 0; r < 4; ++r) tv[r] = f2b(lrelu(acc[i][j][r]));
      *reinterpret_cast<us4*>(
          &TT[(wc * 32 + j * 16 + (lane & 15)) * 72 + wr * 32 + i * 16 + (lane >> 4) * 4]) = tv;
    }
  {  // residual x tile [o][n]
    int o = tid >> 2, ms = (tid & 3) * 16;
    const float* xs = &x[((size_t)(row0 + o) << 10) + col0 + ms];
#pragma unroll
    for (int q = 0; q < 4; ++q)
      *reinterpret_cast<f32x4*>(&Xres[o * 68 + ms + q * 4]) =
          *reinterpret_cast<const f32x4*>(xs + q * 4);
  }
  {  // energy partial out
#pragma unroll
    for (int j = 0; j < 4; ++j)
#pragma unroll
      for (int r = 0; r < 4; ++r)
        en_part[((size_t)blockIdx.x * Bv + b) * 4096 +
                (wave * 16 + (lane >> 4) * 4 + r) * 64 + j * 16 + (lane & 15)] = accE[j][r];
  }
  __syncthreads();
  // chanmix: x1[o][n] = x + lrelu(Wsw @ t + bsw)
  bf16x8 afw[2];
#pragma unroll
  for (int ks = 0; ks < 2; ++ks)
    afw[ks] = *reinterpret_cast<const bf16x8*>(
        &WswB[(wave * 16 + (lane & 15)) * 64 + ks * 32 + (lane >> 4) * 8]);
  f32x4 acc2[4];
#pragma unroll
  for (int j = 0; j < 4; ++j) acc2[j] = (f32x4){0.f, 0.f, 0.f, 0.f};
#pragma unroll
  for (int ks = 0; ks < 2; ++ks)
#pragma unroll
    for (int j = 0; j < 4; ++j) {
      bf16x8 bfr = *reinterpret_cast<const bf16x8*>(
          &TT[(j * 16 + (lane & 15)) * 72 + ks * 32 + (lane >> 4) * 8]);
      acc2[j] = __builtin_amdgcn_mfma_f32_16x16x32_bf16(afw[ks], bfr, acc2[j], 0, 0, 0);
    }
  f32x4 bs4 = *reinterpret_cast<const f32x4*>(&bsw[wave * 16 + (lane >> 4) * 4]);
#pragma unroll
  for (int j = 0; j < 4; ++j)
#pragma unroll
    for (int r = 0; r < 4; ++r) {
      int o = wave * 16 + (lane >> 4) * 4 + r;
      int nl = j * 16 + (lane & 15);
      x1b[((size_t)(row0 + o) << 10) + col0 + nl] =
          f2b(Xres[o * 68 + nl] + lrelu(acc2[j][r] + bs4[r]));
    }
}

// ---------------------------------------------------------------------------
// bn_att: attention = BN(rowmax(en) - en), bf16 out; en = sum of 16 partials.
// ---------------------------------------------------------------------------
__global__ __launch_bounds__(256)
void bn_att_kernel(const float* __restrict__ en, const float* __restrict__ bng,
                   const float* __restrict__ bnb, unsigned short* __restrict__ att) {
  __shared__ float red[8];
  const int c = blockIdx.x;
  const int tid = threadIdx.x, wave = tid >> 6, d = tid & 63;
  const size_t PS = (size_t)Bv * 4096;
  float v[8];
  float sum = 0.f, sumsq = 0.f;
#pragma unroll
  for (int i = 0; i < 8; ++i) {
    int b = wave * 8 + i;
    float e = 0.f;
#pragma unroll
    for (int p = 0; p < 16; ++p) e += en[(size_t)p * PS + (size_t)b * 4096 + c * 64 + d];
    float m = e;
#pragma unroll
    for (int o = 32; o > 0; o >>= 1) m = fmaxf(m, __shfl_xor(m, o));
    v[i] = m - e;
    sum += v[i]; sumsq += v[i] * v[i];
  }
#pragma unroll
  for (int o = 32; o > 0; o >>= 1) { sum += __shfl_xor(sum, o); sumsq += __shfl_xor(sumsq, o); }
  if (d == 0) { red[wave] = sum; red[4 + wave] = sumsq; }
  __syncthreads();
  float S = red[0] + red[1] + red[2] + red[3];
  float SQ = red[4] + red[5] + red[6] + red[7];
  const float inv = 1.f / (float)(Bv * Cv);
  float mu = S * inv;
  float var = SQ * inv - mu * mu;
  float rs = rsqrtf(var + 1e-5f);
  float g = bng[c], be = bnb[c];
#pragma unroll
  for (int i = 0; i < 8; ++i) {
    int b = wave * 8 + i;
    att[(size_t)b * 4096 + c * 64 + d] = f2b(g * (v[i] - mu) * rs + be);
  }
}

// ---------------------------------------------------------------------------
// dynmega: per block (m-tile, b), full n, fused W_dw epilogue, 2-buffer
// double-buffered staging, FULLY UNROLLED 16-chunk loop.
// ---------------------------------------------------------------------------
__global__ __launch_bounds__(256)
void dynmega_kernel(const unsigned short* __restrict__ xbT,
                    const unsigned short* __restrict__ x1b,
                    const unsigned short* __restrict__ attB,
                    const unsigned short* __restrict__ WcmB,
                    const unsigned short* __restrict__ WdwB,
                    const float* __restrict__ x, const float* __restrict__ bcm,
                    const float* __restrict__ bdw, const float* __restrict__ gamma_p,
                    float* __restrict__ dout) {
  __shared__ __align__(16) unsigned short XG[64 * 72];
  __shared__ __align__(16) char buf[32768];  // 2 x 16KB {WT 8KB, X1 8KB}
  __shared__ __align__(16) unsigned short SBt[4 * 16 * 72];
  const int tid = threadIdx.x, wave = tid >> 6, lane = tid & 63;
  const int m0 = blockIdx.x * 64, b = blockIdx.y;
  // ---- head: xglb tile -> XG ----
  {
    unsigned short* XB = (unsigned short*)buf;
    float* Xr = (float*)(buf + 8192);
    stage_tile(&xbT[((size_t)b * 1024 + m0) * 64], 64, XB, wave, lane);
    {
      int o = tid >> 2, ms = (tid & 3) * 16;
      const float* xs = &x[((size_t)(b * 64 + o) << 10) + m0 + ms];
#pragma unroll
      for (int q = 0; q < 4; ++q)
        *reinterpret_cast<f32x4*>(&Xr[o * 68 + ms + q * 4]) =
            *reinterpret_cast<const f32x4*>(xs + q * 4);
    }
    __syncthreads();
    bf16x8 afA[2];
#pragma unroll
    for (int ks = 0; ks < 2; ++ks)
      afA[ks] = *reinterpret_cast<const bf16x8*>(
          &attB[(size_t)b * 4096 + (wave * 16 + (lane & 15)) * 64 + ks * 32 + (lane >> 4) * 8]);
    const float g0 = gamma_p[0];
#pragma unroll
    for (int j = 0; j < 4; ++j) {
      f32x4 ah = (f32x4){0.f, 0.f, 0.f, 0.f};
#pragma unroll
      for (int ks = 0; ks < 2; ++ks) {
        bf16x8 bfh = fragr(XB, j * 16 + (lane & 15), ks, lane);
        ah = __builtin_amdgcn_mfma_f32_16x16x32_bf16(afA[ks], bfh, ah, 0, 0, 0);
      }
      us4 gv;
#pragma unroll
      for (int r = 0; r < 4; ++r)
        gv[r] =
            f2b(g0 * ah[r] + Xr[(wave * 16 + (lane >> 4) * 4 + r) * 68 + j * 16 + (lane & 15)]);
      *reinterpret_cast<us4*>(
          &XG[(j * 16 + (lane & 15)) * 72 + wave * 16 + (lane >> 4) * 4]) = gv;
    }
  }
  __syncthreads();  // XG ready; buf reusable
  bf16x8 xgf[2];
#pragma unroll
  for (int ks = 0; ks < 2; ++ks)
    xgf[ks] = *reinterpret_cast<const bf16x8*>(
        &XG[(wave * 16 + (lane & 15)) * 72 + ks * 32 + (lane >> 4) * 8]);
  stage_tile(&WcmB[0], 64, (unsigned short*)buf, wave, lane);
  stage_tile(&x1b[(size_t)b * 65536], 1024, (unsigned short*)(buf + 8192), wave, lane);
  __syncthreads();
  f32x4 accy[4];
#pragma unroll
  for (int j = 0; j < 4; ++j) accy[j] = (f32x4){0.f, 0.f, 0.f, 0.f};
  unsigned short* SB = &SBt[wave * 16 * 72];
#pragma unroll
  for (int ch = 0; ch < 16; ++ch) {
    const int cur = ch & 1;
    unsigned short* WTcur = (unsigned short*)(buf + cur * 16384);
    unsigned short* X1cur = (unsigned short*)(buf + cur * 16384 + 8192);
    if (ch < 15) {
      char* nxt = buf + (cur ^ 1) * 16384;
      stage_tile(&WcmB[(size_t)(ch + 1) * 4096], 64, (unsigned short*)nxt, wave, lane);
      stage_tile(&x1b[(size_t)b * 65536 + (ch + 1) * 64], 1024, (unsigned short*)(nxt + 8192),
                 wave, lane);
    }
    // stage1: S[n][m-strip] = sigmoid(Wcm . xglb + bcm) -> SB (wave-private)
#pragma unroll
    for (int i = 0; i < 4; ++i) {
      f32x4 s = (f32x4){0.f, 0.f, 0.f, 0.f};
#pragma unroll
      for (int ks = 0; ks < 2; ++ks) {
        bf16x8 af = fragr(WTcur, i * 16 + (lane & 15), ks, lane);
        s = __builtin_amdgcn_mfma_f32_16x16x32_bf16(af, xgf[ks], s, 0, 0, 0);
      }
      f32x4 bc4 = *reinterpret_cast<const f32x4*>(&bcm[ch * 64 + i * 16 + (lane >> 4) * 4]);
      us4 sv;
#pragma unroll
      for (int r = 0; r < 4; ++r) sv[r] = f2b(sigmoidf_(s[r] + bc4[r]));
      *reinterpret_cast<us4*>(&SB[(lane & 15) * 72 + i * 16 + (lane >> 4) * 4]) = sv;
    }
    // stage2: accy[c][m-strip] += x1 . S
#pragma unroll
    for (int ks = 0; ks < 2; ++ks) {
      bf16x8 b2 = *reinterpret_cast<const bf16x8*>(
          &SB[(lane & 15) * 72 + ks * 32 + (lane >> 4) * 8]);
#pragma unroll
      for (int jc = 0; jc < 4; ++jc) {
        bf16x8 a2 = fragr(X1cur, jc * 16 + (lane & 15), ks, lane);
        accy[jc] = __builtin_amdgcn_mfma_f32_16x16x32_bf16(a2, b2, accy[jc], 0, 0, 0);
      }
    }
    __syncthreads();
  }
  // epilogue (wave-private SB reuse): y1 = lrelu(accy) -> YT; out = lrelu(Wdw@y1+bdw)
  unsigned short* YT = SB;
#pragma unroll
  for (int jc = 0; jc < 4; ++jc) {
    us4 yv;
#pragma unroll
    for (int r = 0; r < 4; ++r) yv[r] = f2b(lrelu(accy[jc][r]));
    *reinterpret_cast<us4*>(&YT[(lane & 15) * 72 + jc * 16 + (lane >> 4) * 4]) = yv;
  }
  bf16x8 afW[4][2];
#pragma unroll
  for (int jo = 0; jo < 4; ++jo)
#pragma unroll
    for (int ks = 0; ks < 2; ++ks)
      afW[jo][ks] = *reinterpret_cast<const bf16x8*>(
          &WdwB[(jo * 16 + (lane & 15)) * 64 + ks * 32 + (lane >> 4) * 8]);
  f32x4 accf[4];
#pragma unroll
  for (int j = 0; j < 4; ++j) accf[j] = (f32x4){0.f, 0.f, 0.f, 0.f};
#pragma unroll
  for (int ks = 0; ks < 2; ++ks) {
    bf16x8 yf = *reinterpret_cast<const bf16x8*>(
        &YT[(lane & 15) * 72 + ks * 32 + (lane >> 4) * 8]);
#pragma unroll
    for (int jo = 0; jo < 4; ++jo)
      accf[jo] = __builtin_amdgcn_mfma_f32_16x16x32_bf16(afW[jo][ks], yf, accf[jo], 0, 0, 0);
  }
#pragma unroll
  for (int jo = 0; jo < 4; ++jo) {
    f32x4 bs4 = *reinterpret_cast<const f32x4*>(&bdw[jo * 16 + (lane >> 4) * 4]);
#pragma unroll
    for (int r = 0; r < 4; ++r) {
      int o = jo * 16 + (lane >> 4) * 4 + r;
      dout[((size_t)(b * 64 + o) << 10) + m0 + wave * 16 + (lane & 15)] =
          lrelu(accf[jo][r] + bs4[r]);
    }
  }
}

extern "C" void kernel_launch(void* const* d_in, const int* in_sizes, int n_in,
                              void* d_out, int out_size, void* d_ws, size_t ws_size,
                              hipStream_t stream) {
  const float* x     = (const float*)d_in[0];
  const float* W_sa  = (const float*)d_in[1];
  const float* W_sw  = (const float*)d_in[2];
  const float* b_sw  = (const float*)d_in[3];
  const float* bn_g  = (const float*)d_in[4];
  const float* bn_b  = (const float*)d_in[5];
  const float* gamma = (const float*)d_in[6];
  const float* W_cm  = (const float*)d_in[7];
  const float* b_cm  = (const float*)d_in[8];
  const float* W_dw  = (const float*)d_in[9];
  const float* b_dw  = (const float*)d_in[10];
  float* out = (float*)d_out;

  char* ws = (char*)d_ws;
  const size_t MB = 1024 * 1024;
  unsigned short* xb     = (unsigned short*)(ws + 0 * MB);    // 4MB
  unsigned short* xbT    = (unsigned short*)(ws + 4 * MB);    // 4MB
  unsigned short* WsaB   = (unsigned short*)(ws + 8 * MB);    // 2MB
  unsigned short* WcmB   = (unsigned short*)(ws + 10 * MB);   // 128KB
  unsigned short* WswB   = (unsigned short*)(ws + 10 * MB + 256 * 1024);  // 8KB
  unsigned short* WdwB   = (unsigned short*)(ws + 10 * MB + 288 * 1024);  // 8KB
  unsigned short* x1b    = (unsigned short*)(ws + 11 * MB);   // 4MB
  float*          enpart = (float*)(ws + 15 * MB);            // 8MB (16 slabs)
  unsigned short* attB   = (unsigned short*)(ws + 23 * MB);   // 256KB

  prep_kernel<<<1060, 256, 0, stream>>>(x, W_sa, W_cm, W_sw, W_dw, xb, xbT, WsaB, WcmB, WswB,
                                        WdwB);
  k1x1_kernel<<<dim3(16, Bv), 256, 0, stream>>>(xb, WsaB, WswB, x, b_sw, x1b, enpart);
  bn_att_kernel<<<Cv, 256, 0, stream>>>(enpart, bn_g, bn_b, attB);
  dynmega_kernel<<<dim3(16, Bv), 256, 0, stream>>>(xbT, x1b, attB, WcmB, WdwB, x, b_cm, b_dw,
                                                   gamma, out);
}

// Round 9
// 95.927 us; speedup vs baseline: 1.0119x; 1.0119x over previous
//
#include <hip/hip_runtime.h>

#define Bv 32
#define Cv 64
#define Nv 1024

typedef __attribute__((ext_vector_type(8))) short bf16x8;
typedef __attribute__((ext_vector_type(4))) float f32x4;
typedef __attribute__((ext_vector_type(8))) unsigned short us8;
typedef __attribute__((ext_vector_type(4))) unsigned short us4;

__device__ __forceinline__ float lrelu(float v) { return v >= 0.f ? v : 0.2f * v; }
__device__ __forceinline__ float sigmoidf_(float z) { return 1.f / (1.f + __expf(-z)); }
__device__ __forceinline__ unsigned short f2b(float f) {
  unsigned int u = __float_as_uint(f);
  unsigned int r = u + 0x7FFFu + ((u >> 16) & 1u);
  return (unsigned short)(r >> 16);
}
__device__ __forceinline__ void gload16(const void* g, void* l) {
  __builtin_amdgcn_global_load_lds((const __attribute__((address_space(1))) void*)g,
                                   (__attribute__((address_space(3))) void*)l, 16, 0, 0);
}
// 64x64 bf16 tile, linear LDS dest, XOR-swizzled global source; granule g of
// row r holds global granule g ^ (r&7). fragr applies the same XOR on read.
__device__ __forceinline__ void stage_tile(const unsigned short* src, size_t stride,
                                           unsigned short* dst, int wave, int lane) {
#pragma unroll
  for (int p = 0; p < 2; ++p) {
    int q = wave * 2 + p;
    int rr = q * 8 + (lane >> 3);
    int gS = ((lane & 7) ^ (rr & 7)) << 3;
    gload16(&src[(size_t)rr * stride + gS], &dst[q * 512]);
  }
}
__device__ __forceinline__ bf16x8 fragr(const unsigned short* buf, int row, int ks, int lane) {
  return *reinterpret_cast<const bf16x8*>(
      &buf[row * 64 + (((ks * 4 + (lane >> 4)) ^ (row & 7)) << 3)]);
}
// XCD-locality decode: dispatch round-robins flat id over 8 XCDs; group all 16
// m-tiles of one batch b onto one XCD (x1b[b]/xbT[b]/Wcm become local-L2 hits).
__device__ __forceinline__ void xcd_decode(int id, int& b, int& mt) {
  int k = id & 7, pos = id >> 3;
  mt = pos & 15;
  b = k + 8 * (pos >> 4);
}

// ---------------------------------------------------------------------------
// prep: f32->bf16 conversions; x read once (straight + transposed).
// ---------------------------------------------------------------------------
__device__ __forceinline__ void cvt8(const float* in, unsigned short* out, int i) {
  const f32x4* p = reinterpret_cast<const f32x4*>(in + (size_t)i * 8);
  f32x4 a = p[0], b = p[1];
  us8 o;
  o[0] = f2b(a[0]); o[1] = f2b(a[1]); o[2] = f2b(a[2]); o[3] = f2b(a[3]);
  o[4] = f2b(b[0]); o[5] = f2b(b[1]); o[6] = f2b(b[2]); o[7] = f2b(b[3]);
  *reinterpret_cast<us8*>(out + (size_t)i * 8) = o;
}

__global__ __launch_bounds__(256)
void prep_kernel(const float* __restrict__ x, const float* __restrict__ Wsa,
                 const float* __restrict__ Wcm, const float* __restrict__ Wsw,
                 const float* __restrict__ Wdw, unsigned short* __restrict__ xb,
                 unsigned short* __restrict__ xbT, unsigned short* __restrict__ WsaB,
                 unsigned short* __restrict__ WcmB, unsigned short* __restrict__ WswB,
                 unsigned short* __restrict__ WdwB) {
  __shared__ unsigned short L[64 * 72];
  const int blk = blockIdx.x, tid = threadIdx.x;
  if (blk < 512) {
    int b = blk >> 4, n0 = (blk & 15) * 64;
    int c = tid >> 2, nseg = (tid & 3) * 16;
    const float* src = &x[((size_t)(b * 64 + c) << 10) + n0 + nseg];
#pragma unroll
    for (int q = 0; q < 4; ++q) {
      f32x4 v = *reinterpret_cast<const f32x4*>(src + q * 4);
      us4 w4;
#pragma unroll
      for (int e = 0; e < 4; ++e) {
        unsigned short bf = f2b(v[e]);
        L[(nseg + q * 4 + e) * 72 + c] = bf;
        w4[e] = bf;
      }
      *reinterpret_cast<us4*>(&xb[((size_t)(b * 64 + c) << 10) + n0 + nseg + q * 4]) = w4;
    }
    __syncthreads();
    int n = tid >> 2, cs = (tid & 3) * 16;
    us8 a = *reinterpret_cast<const us8*>(&L[n * 72 + cs]);
    us8 bq = *reinterpret_cast<const us8*>(&L[n * 72 + cs + 8]);
    unsigned short* dst = &xbT[(((size_t)b << 10) + n0 + n) * 64 + cs];
    *reinterpret_cast<us8*>(dst) = a;
    *reinterpret_cast<us8*>(dst + 8) = bq;
  } else if (blk < 1024) {
    cvt8(Wsa, WsaB, (blk - 512) * 256 + tid);
  } else if (blk < 1056) {
    cvt8(Wcm, WcmB, (blk - 1024) * 256 + tid);
  } else if (blk < 1058) {
    cvt8(Wsw, WswB, (blk - 1056) * 256 + tid);
  } else {
    cvt8(Wdw, WdwB, (blk - 1058) * 256 + tid);
  }
}

// ---------------------------------------------------------------------------
// k1x1: fused  t = lrelu(x @ Wsa^T)  ->  x1 = x + lrelu(Wsw @ t + bsw)
// 2-buffer dbuf staging, runtime K-loop (R5 structure). XCD-grouped by b.
// Energy balanced: m-tile mt accumulates its own K-slab partial -> en_part[mt][b].
// ---------------------------------------------------------------------------
__global__ __launch_bounds__(256)
void k1x1_kernel(const unsigned short* __restrict__ xb,
                 const unsigned short* __restrict__ WsaB,
                 const unsigned short* __restrict__ WswB,
                 const float* __restrict__ x, const float* __restrict__ bsw,
                 unsigned short* __restrict__ x1b, float* __restrict__ en_part) {
  __shared__ __align__(16) unsigned short As[2][4096];
  __shared__ __align__(16) unsigned short Bs[2][4096];
  __shared__ __align__(16) unsigned short TT[64 * 72];
  __shared__ __align__(16) float Xres[64 * 68];
  const int tid = threadIdx.x, wave = tid >> 6, lane = tid & 63;
  int b, mt;
  xcd_decode(blockIdx.x, b, mt);
  const int col0 = mt * 64, row0 = b * 64;
  const int wr = wave >> 1, wc = wave & 1;
  f32x4 acc[2][2], accE[4];
#pragma unroll
  for (int i = 0; i < 2; ++i)
#pragma unroll
    for (int j = 0; j < 2; ++j) acc[i][j] = (f32x4){0.f, 0.f, 0.f, 0.f};
#pragma unroll
  for (int j = 0; j < 4; ++j) accE[j] = (f32x4){0.f, 0.f, 0.f, 0.f};

  stage_tile(&xb[(size_t)row0 * Nv], Nv, As[0], wave, lane);
  stage_tile(&WsaB[(size_t)col0 * Nv], Nv, Bs[0], wave, lane);
  __syncthreads();
  for (int t = 0; t < 16; ++t) {
    const int cur = t & 1;
    if (t < 15) {
      stage_tile(&xb[(size_t)row0 * Nv + (t + 1) * 64], Nv, As[cur ^ 1], wave, lane);
      stage_tile(&WsaB[(size_t)col0 * Nv + (t + 1) * 64], Nv, Bs[cur ^ 1], wave, lane);
    }
#pragma unroll
    for (int ks = 0; ks < 2; ++ks) {
      bf16x8 af[2], bfg[2];
#pragma unroll
      for (int i = 0; i < 2; ++i) af[i] = fragr(As[cur], wr * 32 + i * 16 + (lane & 15), ks, lane);
#pragma unroll
      for (int j = 0; j < 2; ++j) bfg[j] = fragr(Bs[cur], wc * 32 + j * 16 + (lane & 15), ks, lane);
#pragma unroll
      for (int i = 0; i < 2; ++i)
#pragma unroll
        for (int j = 0; j < 2; ++j)
          acc[i][j] = __builtin_amdgcn_mfma_f32_16x16x32_bf16(af[i], bfg[j], acc[i][j], 0, 0, 0);
    }
    if (t == mt) {  // balanced energy partial
#pragma unroll
      for (int ks = 0; ks < 2; ++ks) {
        bf16x8 aE = fragr(As[cur], wave * 16 + (lane & 15), ks, lane);
#pragma unroll
        for (int j = 0; j < 4; ++j) {
          bf16x8 bE = fragr(As[cur], j * 16 + (lane & 15), ks, lane);
          accE[j] = __builtin_amdgcn_mfma_f32_16x16x32_bf16(aE, bE, accE[j], 0, 0, 0);
        }
      }
    }
    __syncthreads();
  }
  // t-tile -> TT [n][c]
#pragma unroll
  for (int i = 0; i < 2; ++i)
#pragma unroll
    for (int j = 0; j < 2; ++j) {
      us4 tv;
#pragma unroll
      for (int r = 0; r < 4; ++r) tv[r] = f2b(lrelu(acc[i][j][r]));
      *reinterpret_cast<us4*>(
          &TT[(wc * 32 + j * 16 + (lane & 15)) * 72 + wr * 32 + i * 16 + (lane >> 4) * 4]) = tv;
    }
  {  // residual x tile [o][n]
    int o = tid >> 2, ms = (tid & 3) * 16;
    const float* xs = &x[((size_t)(row0 + o) << 10) + col0 + ms];
#pragma unroll
    for (int q = 0; q < 4; ++q)
      *reinterpret_cast<f32x4*>(&Xres[o * 68 + ms + q * 4]) =
          *reinterpret_cast<const f32x4*>(xs + q * 4);
  }
  {  // energy partial out
#pragma unroll
    for (int j = 0; j < 4; ++j)
#pragma unroll
      for (int r = 0; r < 4; ++r)
        en_part[((size_t)mt * Bv + b) * 4096 +
                (wave * 16 + (lane >> 4) * 4 + r) * 64 + j * 16 + (lane & 15)] = accE[j][r];
  }
  __syncthreads();
  // chanmix: x1[o][n] = x + lrelu(Wsw @ t + bsw)
  bf16x8 afw[2];
#pragma unroll
  for (int ks = 0; ks < 2; ++ks)
    afw[ks] = *reinterpret_cast<const bf16x8*>(
        &WswB[(wave * 16 + (lane & 15)) * 64 + ks * 32 + (lane >> 4) * 8]);
  f32x4 acc2[4];
#pragma unroll
  for (int j = 0; j < 4; ++j) acc2[j] = (f32x4){0.f, 0.f, 0.f, 0.f};
#pragma unroll
  for (int ks = 0; ks < 2; ++ks)
#pragma unroll
    for (int j = 0; j < 4; ++j) {
      bf16x8 bfr = *reinterpret_cast<const bf16x8*>(
          &TT[(j * 16 + (lane & 15)) * 72 + ks * 32 + (lane >> 4) * 8]);
      acc2[j] = __builtin_amdgcn_mfma_f32_16x16x32_bf16(afw[ks], bfr, acc2[j], 0, 0, 0);
    }
  f32x4 bs4 = *reinterpret_cast<const f32x4*>(&bsw[wave * 16 + (lane >> 4) * 4]);
#pragma unroll
  for (int j = 0; j < 4; ++j)
#pragma unroll
    for (int r = 0; r < 4; ++r) {
      int o = wave * 16 + (lane >> 4) * 4 + r;
      int nl = j * 16 + (lane & 15);
      x1b[((size_t)(row0 + o) << 10) + col0 + nl] =
          f2b(Xres[o * 68 + nl] + lrelu(acc2[j][r] + bs4[r]));
    }
}

// ---------------------------------------------------------------------------
// bn_att: attention = BN(rowmax(en) - en), bf16 out; en = sum of 16 partials.
// ---------------------------------------------------------------------------
__global__ __launch_bounds__(256)
void bn_att_kernel(const float* __restrict__ en, const float* __restrict__ bng,
                   const float* __restrict__ bnb, unsigned short* __restrict__ att) {
  __shared__ float red[8];
  const int c = blockIdx.x;
  const int tid = threadIdx.x, wave = tid >> 6, d = tid & 63;
  const size_t PS = (size_t)Bv * 4096;
  float v[8];
  float sum = 0.f, sumsq = 0.f;
#pragma unroll
  for (int i = 0; i < 8; ++i) {
    int b = wave * 8 + i;
    float e = 0.f;
#pragma unroll
    for (int p = 0; p < 16; ++p) e += en[(size_t)p * PS + (size_t)b * 4096 + c * 64 + d];
    float m = e;
#pragma unroll
    for (int o = 32; o > 0; o >>= 1) m = fmaxf(m, __shfl_xor(m, o));
    v[i] = m - e;
    sum += v[i]; sumsq += v[i] * v[i];
  }
#pragma unroll
  for (int o = 32; o > 0; o >>= 1) { sum += __shfl_xor(sum, o); sumsq += __shfl_xor(sumsq, o); }
  if (d == 0) { red[wave] = sum; red[4 + wave] = sumsq; }
  __syncthreads();
  float S = red[0] + red[1] + red[2] + red[3];
  float SQ = red[4] + red[5] + red[6] + red[7];
  const float inv = 1.f / (float)(Bv * Cv);
  float mu = S * inv;
  float var = SQ * inv - mu * mu;
  float rs = rsqrtf(var + 1e-5f);
  float g = bng[c], be = bnb[c];
#pragma unroll
  for (int i = 0; i < 8; ++i) {
    int b = wave * 8 + i;
    att[(size_t)b * 4096 + c * 64 + d] = f2b(g * (v[i] - mu) * rs + be);
  }
}

// ---------------------------------------------------------------------------
// dynmega: per block (m-tile, b), full n, fused W_dw epilogue, 2-buffer dbuf,
// runtime 16-chunk loop (R5 structure). XCD-grouped by b; bcm cached in LDS.
// ---------------------------------------------------------------------------
__global__ __launch_bounds__(256)
void dynmega_kernel(const unsigned short* __restrict__ xbT,
                    const unsigned short* __restrict__ x1b,
                    const unsigned short* __restrict__ attB,
                    const unsigned short* __restrict__ WcmB,
                    const unsigned short* __restrict__ WdwB,
                    const float* __restrict__ x, const float* __restrict__ bcm,
                    const float* __restrict__ bdw, const float* __restrict__ gamma_p,
                    float* __restrict__ dout) {
  __shared__ __align__(16) unsigned short XG[64 * 72];
  __shared__ __align__(16) char buf[32768];  // 2 x 16KB {WT 8KB, X1 8KB}
  __shared__ __align__(16) unsigned short SBt[4 * 16 * 72];
  __shared__ __align__(16) float BC[1024];
  const int tid = threadIdx.x, wave = tid >> 6, lane = tid & 63;
  int b, mt;
  xcd_decode(blockIdx.x, b, mt);
  const int m0 = mt * 64;
  // ---- head: bcm -> LDS; xglb tile -> XG ----
  *reinterpret_cast<f32x4*>(&BC[tid * 4]) = *reinterpret_cast<const f32x4*>(&bcm[tid * 4]);
  {
    unsigned short* XB = (unsigned short*)buf;
    float* Xr = (float*)(buf + 8192);
    stage_tile(&xbT[((size_t)b * 1024 + m0) * 64], 64, XB, wave, lane);
    {
      int o = tid >> 2, ms = (tid & 3) * 16;
      const float* xs = &x[((size_t)(b * 64 + o) << 10) + m0 + ms];
#pragma unroll
      for (int q = 0; q < 4; ++q)
        *reinterpret_cast<f32x4*>(&Xr[o * 68 + ms + q * 4]) =
            *reinterpret_cast<const f32x4*>(xs + q * 4);
    }
    __syncthreads();
    bf16x8 afA[2];
#pragma unroll
    for (int ks = 0; ks < 2; ++ks)
      afA[ks] = *reinterpret_cast<const bf16x8*>(
          &attB[(size_t)b * 4096 + (wave * 16 + (lane & 15)) * 64 + ks * 32 + (lane >> 4) * 8]);
    const float g0 = gamma_p[0];
#pragma unroll
    for (int j = 0; j < 4; ++j) {
      f32x4 ah = (f32x4){0.f, 0.f, 0.f, 0.f};
#pragma unroll
      for (int ks = 0; ks < 2; ++ks) {
        bf16x8 bfh = fragr(XB, j * 16 + (lane & 15), ks, lane);
        ah = __builtin_amdgcn_mfma_f32_16x16x32_bf16(afA[ks], bfh, ah, 0, 0, 0);
      }
      us4 gv;
#pragma unroll
      for (int r = 0; r < 4; ++r)
        gv[r] =
            f2b(g0 * ah[r] + Xr[(wave * 16 + (lane >> 4) * 4 + r) * 68 + j * 16 + (lane & 15)]);
      *reinterpret_cast<us4*>(
          &XG[(j * 16 + (lane & 15)) * 72 + wave * 16 + (lane >> 4) * 4]) = gv;
    }
  }
  __syncthreads();  // XG/BC ready; buf reusable
  bf16x8 xgf[2];
#pragma unroll
  for (int ks = 0; ks < 2; ++ks)
    xgf[ks] = *reinterpret_cast<const bf16x8*>(
        &XG[(wave * 16 + (lane & 15)) * 72 + ks * 32 + (lane >> 4) * 8]);
  stage_tile(&WcmB[0], 64, (unsigned short*)buf, wave, lane);
  stage_tile(&x1b[(size_t)b * 65536], 1024, (unsigned short*)(buf + 8192), wave, lane);
  __syncthreads();
  f32x4 accy[4];
#pragma unroll
  for (int j = 0; j < 4; ++j) accy[j] = (f32x4){0.f, 0.f, 0.f, 0.f};
  unsigned short* SB = &SBt[wave * 16 * 72];
  for (int ch = 0; ch < 16; ++ch) {
    const int cur = ch & 1;
    unsigned short* WTcur = (unsigned short*)(buf + cur * 16384);
    unsigned short* X1cur = (unsigned short*)(buf + cur * 16384 + 8192);
    if (ch < 15) {
      char* nxt = buf + (cur ^ 1) * 16384;
      stage_tile(&WcmB[(size_t)(ch + 1) * 4096], 64, (unsigned short*)nxt, wave, lane);
      stage_tile(&x1b[(size_t)b * 65536 + (ch + 1) * 64], 1024, (unsigned short*)(nxt + 8192),
                 wave, lane);
    }
    // stage1: S[n][m-strip] = sigmoid(Wcm . xglb + bcm) -> SB (wave-private)
#pragma unroll
    for (int i = 0; i < 4; ++i) {
      f32x4 s = (f32x4){0.f, 0.f, 0.f, 0.f};
#pragma unroll
      for (int ks = 0; ks < 2; ++ks) {
        bf16x8 af = fragr(WTcur, i * 16 + (lane & 15), ks, lane);
        s = __builtin_amdgcn_mfma_f32_16x16x32_bf16(af, xgf[ks], s, 0, 0, 0);
      }
      f32x4 bc4 = *reinterpret_cast<const f32x4*>(&BC[ch * 64 + i * 16 + (lane >> 4) * 4]);
      us4 sv;
#pragma unroll
      for (int r = 0; r < 4; ++r) sv[r] = f2b(sigmoidf_(s[r] + bc4[r]));
      *reinterpret_cast<us4*>(&SB[(lane & 15) * 72 + i * 16 + (lane >> 4) * 4]) = sv;
    }
    // stage2: accy[c][m-strip] += x1 . S
#pragma unroll
    for (int ks = 0; ks < 2; ++ks) {
      bf16x8 b2 = *reinterpret_cast<const bf16x8*>(
          &SB[(lane & 15) * 72 + ks * 32 + (lane >> 4) * 8]);
#pragma unroll
      for (int jc = 0; jc < 4; ++jc) {
        bf16x8 a2 = fragr(X1cur, jc * 16 + (lane & 15), ks, lane);
        accy[jc] = __builtin_amdgcn_mfma_f32_16x16x32_bf16(a2, b2, accy[jc], 0, 0, 0);
      }
    }
    __syncthreads();
  }
  // epilogue (wave-private SB reuse): y1 = lrelu(accy) -> YT; out = lrelu(Wdw@y1+bdw)
  unsigned short* YT = SB;
#pragma unroll
  for (int jc = 0; jc < 4; ++jc) {
    us4 yv;
#pragma unroll
    for (int r = 0; r < 4; ++r) yv[r] = f2b(lrelu(accy[jc][r]));
    *reinterpret_cast<us4*>(&YT[(lane & 15) * 72 + jc * 16 + (lane >> 4) * 4]) = yv;
  }
  bf16x8 afW[4][2];
#pragma unroll
  for (int jo = 0; jo < 4; ++jo)
#pragma unroll
    for (int ks = 0; ks < 2; ++ks)
      afW[jo][ks] = *reinterpret_cast<const bf16x8*>(
          &WdwB[(jo * 16 + (lane & 15)) * 64 + ks * 32 + (lane >> 4) * 8]);
  f32x4 accf[4];
#pragma unroll
  for (int j = 0; j < 4; ++j) accf[j] = (f32x4){0.f, 0.f, 0.f, 0.f};
#pragma unroll
  for (int ks = 0; ks < 2; ++ks) {
    bf16x8 yf = *reinterpret_cast<const bf16x8*>(
        &YT[(lane & 15) * 72 + ks * 32 + (lane >> 4) * 8]);
#pragma unroll
    for (int jo = 0; jo < 4; ++jo)
      accf[jo] = __builtin_amdgcn_mfma_f32_16x16x32_bf16(afW[jo][ks], yf, accf[jo], 0, 0, 0);
  }
#pragma unroll
  for (int jo = 0; jo < 4; ++jo) {
    f32x4 bs4 = *reinterpret_cast<const f32x4*>(&bdw[jo * 16 + (lane >> 4) * 4]);
#pragma unroll
    for (int r = 0; r < 4; ++r) {
      int o = jo * 16 + (lane >> 4) * 4 + r;
      dout[((size_t)(b * 64 + o) << 10) + m0 + wave * 16 + (lane & 15)] =
          lrelu(accf[jo][r] + bs4[r]);
    }
  }
}

extern "C" void kernel_launch(void* const* d_in, const int* in_sizes, int n_in,
                              void* d_out, int out_size, void* d_ws, size_t ws_size,
                              hipStream_t stream) {
  const float* x     = (const float*)d_in[0];
  const float* W_sa  = (const float*)d_in[1];
  const float* W_sw  = (const float*)d_in[2];
  const float* b_sw  = (const float*)d_in[3];
  const float* bn_g  = (const float*)d_in[4];
  const float* bn_b  = (const float*)d_in[5];
  const float* gamma = (const float*)d_in[6];
  const float* W_cm  = (const float*)d_in[7];
  const float* b_cm  = (const float*)d_in[8];
  const float* W_dw  = (const float*)d_in[9];
  const float* b_dw  = (const float*)d_in[10];
  float* out = (float*)d_out;

  char* ws = (char*)d_ws;
  const size_t MB = 1024 * 1024;
  unsigned short* xb     = (unsigned short*)(ws + 0 * MB);    // 4MB
  unsigned short* xbT    = (unsigned short*)(ws + 4 * MB);    // 4MB
  unsigned short* WsaB   = (unsigned short*)(ws + 8 * MB);    // 2MB
  unsigned short* WcmB   = (unsigned short*)(ws + 10 * MB);   // 128KB
  unsigned short* WswB   = (unsigned short*)(ws + 10 * MB + 256 * 1024);  // 8KB
  unsigned short* WdwB   = (unsigned short*)(ws + 10 * MB + 288 * 1024);  // 8KB
  unsigned short* x1b    = (unsigned short*)(ws + 11 * MB);   // 4MB
  float*          enpart = (float*)(ws + 15 * MB);            // 8MB (16 slabs)
  unsigned short* attB   = (unsigned short*)(ws + 23 * MB);   // 256KB

  prep_kernel<<<1060, 256, 0, stream>>>(x, W_sa, W_cm, W_sw, W_dw, xb, xbT, WsaB, WcmB, WswB,
                                        WdwB);
  k1x1_kernel<<<512, 256, 0, stream>>>(xb, WsaB, WswB, x, b_sw, x1b, enpart);
  bn_att_kernel<<<Cv, 256, 0, stream>>>(enpart, bn_g, bn_b, attB);
  dynmega_kernel<<<512, 256, 0, stream>>>(xbT, x1b, attB, WcmB, WdwB, x, b_cm, b_dw,
                                          gamma, out);
}

// Round 10
// 58.586 us; speedup vs baseline: 1.6569x; 1.6374x over previous
//
#include <hip/hip_runtime.h>
#include <hip/hip_bf16.h>

#define Bv 32
#define Cv 64
#define Nv 1024

typedef __attribute__((ext_vector_type(8))) short bf16x8;
typedef __attribute__((ext_vector_type(4))) float f32x4;
typedef __attribute__((ext_vector_type(8))) unsigned short us8;
typedef __attribute__((ext_vector_type(4))) unsigned short us4;

__device__ __forceinline__ float lrelu(float v) { return v >= 0.f ? v : 0.2f * v; }
// fast sigmoid: v_exp + v_rcp (no IEEE divide sequence); err ~1e-6 << bf16 ulp
__device__ __forceinline__ float sigmoidf_(float z) {
  return __builtin_amdgcn_rcpf(1.f + __expf(-z));
}
__device__ __forceinline__ unsigned short f2b(float f) {
  unsigned int u = __float_as_uint(f);
  unsigned int r = u + 0x7FFFu + ((u >> 16) & 1u);
  return (unsigned short)(r >> 16);
}
// HW-convert path (compiler pairs adjacent casts into v_cvt_pk_bf16_f32)
__device__ __forceinline__ unsigned short f2bh(float f) {
  __hip_bfloat16 h = __float2bfloat16(f);
  return reinterpret_cast<unsigned short&>(h);
}
__device__ __forceinline__ void gload16(const void* g, void* l) {
  __builtin_amdgcn_global_load_lds((const __attribute__((address_space(1))) void*)g,
                                   (__attribute__((address_space(3))) void*)l, 16, 0, 0);
}
// 64x64 bf16 tile, linear LDS dest, XOR-swizzled global source; granule g of
// row r holds global granule g ^ (r&7). fragr applies the same XOR on read.
__device__ __forceinline__ void stage_tile(const unsigned short* src, size_t stride,
                                           unsigned short* dst, int wave, int lane) {
#pragma unroll
  for (int p = 0; p < 2; ++p) {
    int q = wave * 2 + p;
    int rr = q * 8 + (lane >> 3);
    int gS = ((lane & 7) ^ (rr & 7)) << 3;
    gload16(&src[(size_t)rr * stride + gS], &dst[q * 512]);
  }
}
__device__ __forceinline__ bf16x8 fragr(const unsigned short* buf, int row, int ks, int lane) {
  return *reinterpret_cast<const bf16x8*>(
      &buf[row * 64 + (((ks * 4 + (lane >> 4)) ^ (row & 7)) << 3)]);
}

// ---------------------------------------------------------------------------
// prep: all f32->bf16 conversions + xT transpose, one launch.  (R5-exact)
// ---------------------------------------------------------------------------
__device__ __forceinline__ void cvt8(const float* in, unsigned short* out, int i) {
  const f32x4* p = reinterpret_cast<const f32x4*>(in + (size_t)i * 8);
  f32x4 a = p[0], b = p[1];
  us8 o;
  o[0] = f2b(a[0]); o[1] = f2b(a[1]); o[2] = f2b(a[2]); o[3] = f2b(a[3]);
  o[4] = f2b(b[0]); o[5] = f2b(b[1]); o[6] = f2b(b[2]); o[7] = f2b(b[3]);
  *reinterpret_cast<us8*>(out + (size_t)i * 8) = o;
}

__global__ __launch_bounds__(256)
void prep_kernel(const float* __restrict__ x, const float* __restrict__ Wsa,
                 const float* __restrict__ Wcm, const float* __restrict__ Wsw,
                 const float* __restrict__ Wdw, unsigned short* __restrict__ xb,
                 unsigned short* __restrict__ xbT, unsigned short* __restrict__ WsaB,
                 unsigned short* __restrict__ WcmB, unsigned short* __restrict__ WswB,
                 unsigned short* __restrict__ WdwB) {
  __shared__ unsigned short L[64 * 72];
  const int blk = blockIdx.x, tid = threadIdx.x;
  if (blk < 1024) {
    cvt8(x, xb, blk * 256 + tid);
  } else if (blk < 1536) {
    int id = blk - 1024;
    int b = id >> 4, n0 = (id & 15) * 64;
    int c = tid >> 2, nseg = (tid & 3) * 16;
    const float* src = &x[((size_t)(b * 64 + c) << 10) + n0 + nseg];
#pragma unroll
    for (int q = 0; q < 4; ++q) {
      f32x4 v = *reinterpret_cast<const f32x4*>(src + q * 4);
#pragma unroll
      for (int e = 0; e < 4; ++e) L[(nseg + q * 4 + e) * 72 + c] = f2b(v[e]);
    }
    __syncthreads();
    int n = tid >> 2, cs = (tid & 3) * 16;
    us8 a = *reinterpret_cast<const us8*>(&L[n * 72 + cs]);
    us8 bq = *reinterpret_cast<const us8*>(&L[n * 72 + cs + 8]);
    unsigned short* dst = &xbT[(((size_t)b << 10) + n0 + n) * 64 + cs];
    *reinterpret_cast<us8*>(dst) = a;
    *reinterpret_cast<us8*>(dst + 8) = bq;
  } else if (blk < 2048) {
    cvt8(Wsa, WsaB, (blk - 1536) * 256 + tid);
  } else if (blk < 2080) {
    cvt8(Wcm, WcmB, (blk - 2048) * 256 + tid);
  } else if (blk < 2082) {
    cvt8(Wsw, WswB, (blk - 2080) * 256 + tid);
  } else {
    cvt8(Wdw, WdwB, (blk - 2082) * 256 + tid);
  }
}

// ---------------------------------------------------------------------------
// k1x1: fused  t = lrelu(x @ Wsa^T)  ->  x1 = x + lrelu(Wsw @ t + bsw)
// (R5-exact: 2-buffer dbuf, doEn on blockIdx.x==0)
// ---------------------------------------------------------------------------
__global__ __launch_bounds__(256)
void k1x1_kernel(const unsigned short* __restrict__ xb,
                 const unsigned short* __restrict__ WsaB,
                 const unsigned short* __restrict__ WswB,
                 const float* __restrict__ x, const float* __restrict__ bsw,
                 unsigned short* __restrict__ x1b, float* __restrict__ en) {
  __shared__ __align__(16) unsigned short As[2][4096];
  __shared__ __align__(16) unsigned short Bs[2][4096];
  __shared__ __align__(16) unsigned short TT[64 * 72];
  __shared__ __align__(16) float Xres[64 * 68];
  const int tid = threadIdx.x, wave = tid >> 6, lane = tid & 63;
  const int b = blockIdx.y, col0 = blockIdx.x * 64, row0 = b * 64;
  const int wr = wave >> 1, wc = wave & 1;
  const bool doEn = (blockIdx.x == 0);
  f32x4 acc[2][2], accE[4];
#pragma unroll
  for (int i = 0; i < 2; ++i)
#pragma unroll
    for (int j = 0; j < 2; ++j) acc[i][j] = (f32x4){0.f, 0.f, 0.f, 0.f};
#pragma unroll
  for (int j = 0; j < 4; ++j) accE[j] = (f32x4){0.f, 0.f, 0.f, 0.f};

  stage_tile(&xb[(size_t)row0 * Nv], Nv, As[0], wave, lane);
  stage_tile(&WsaB[(size_t)col0 * Nv], Nv, Bs[0], wave, lane);
  __syncthreads();
  for (int t = 0; t < 16; ++t) {
    const int cur = t & 1;
    if (t < 15) {
      stage_tile(&xb[(size_t)row0 * Nv + (t + 1) * 64], Nv, As[cur ^ 1], wave, lane);
      stage_tile(&WsaB[(size_t)col0 * Nv + (t + 1) * 64], Nv, Bs[cur ^ 1], wave, lane);
    }
#pragma unroll
    for (int ks = 0; ks < 2; ++ks) {
      bf16x8 af[2], bfg[2];
#pragma unroll
      for (int i = 0; i < 2; ++i) af[i] = fragr(As[cur], wr * 32 + i * 16 + (lane & 15), ks, lane);
#pragma unroll
      for (int j = 0; j < 2; ++j) bfg[j] = fragr(Bs[cur], wc * 32 + j * 16 + (lane & 15), ks, lane);
#pragma unroll
      for (int i = 0; i < 2; ++i)
#pragma unroll
        for (int j = 0; j < 2; ++j)
          acc[i][j] = __builtin_amdgcn_mfma_f32_16x16x32_bf16(af[i], bfg[j], acc[i][j], 0, 0, 0);
      if (doEn) {
        bf16x8 aE = fragr(As[cur], wave * 16 + (lane & 15), ks, lane);
#pragma unroll
        for (int j = 0; j < 4; ++j) {
          bf16x8 bE = fragr(As[cur], j * 16 + (lane & 15), ks, lane);
          accE[j] = __builtin_amdgcn_mfma_f32_16x16x32_bf16(aE, bE, accE[j], 0, 0, 0);
        }
      }
    }
    __syncthreads();
  }
  // t-tile -> TT [n][c]
#pragma unroll
  for (int i = 0; i < 2; ++i)
#pragma unroll
    for (int j = 0; j < 2; ++j) {
      us4 tv;
#pragma unroll
      for (int r = 0; r < 4; ++r) tv[r] = f2b(lrelu(acc[i][j][r]));
      *reinterpret_cast<us4*>(
          &TT[(wc * 32 + j * 16 + (lane & 15)) * 72 + wr * 32 + i * 16 + (lane >> 4) * 4]) = tv;
    }
  {  // residual x tile [o][n]
    int o = tid >> 2, ms = (tid & 3) * 16;
    const float* xs = &x[((size_t)(row0 + o) << 10) + col0 + ms];
#pragma unroll
    for (int q = 0; q < 4; ++q)
      *reinterpret_cast<f32x4*>(&Xres[o * 68 + ms + q * 4]) =
          *reinterpret_cast<const f32x4*>(xs + q * 4);
  }
  if (doEn) {
#pragma unroll
    for (int j = 0; j < 4; ++j)
#pragma unroll
      for (int r = 0; r < 4; ++r)
        en[(size_t)b * 4096 + (wave * 16 + (lane >> 4) * 4 + r) * 64 + j * 16 + (lane & 15)] =
            accE[j][r];
  }
  __syncthreads();
  // chanmix: x1[o][n] = x + lrelu(Wsw @ t + bsw)
  bf16x8 afw[2];
#pragma unroll
  for (int ks = 0; ks < 2; ++ks)
    afw[ks] = *reinterpret_cast<const bf16x8*>(
        &WswB[(wave * 16 + (lane & 15)) * 64 + ks * 32 + (lane >> 4) * 8]);
  f32x4 acc2[4];
#pragma unroll
  for (int j = 0; j < 4; ++j) acc2[j] = (f32x4){0.f, 0.f, 0.f, 0.f};
#pragma unroll
  for (int ks = 0; ks < 2; ++ks)
#pragma unroll
    for (int j = 0; j < 4; ++j) {
      bf16x8 bfr = *reinterpret_cast<const bf16x8*>(
          &TT[(j * 16 + (lane & 15)) * 72 + ks * 32 + (lane >> 4) * 8]);
      acc2[j] = __builtin_amdgcn_mfma_f32_16x16x32_bf16(afw[ks], bfr, acc2[j], 0, 0, 0);
    }
  f32x4 bs4 = *reinterpret_cast<const f32x4*>(&bsw[wave * 16 + (lane >> 4) * 4]);
#pragma unroll
  for (int j = 0; j < 4; ++j)
#pragma unroll
    for (int r = 0; r < 4; ++r) {
      int o = wave * 16 + (lane >> 4) * 4 + r;
      int nl = j * 16 + (lane & 15);
      x1b[((size_t)(row0 + o) << 10) + col0 + nl] =
          f2b(Xres[o * 68 + nl] + lrelu(acc2[j][r] + bs4[r]));
    }
}

// ---------------------------------------------------------------------------
// bn_att: attention = BN(rowmax(en) - en), bf16 out. (R5-exact, 1 wave/channel)
// ---------------------------------------------------------------------------
__global__ __launch_bounds__(64)
void bn_att_kernel(const float* __restrict__ en, const float* __restrict__ bng,
                   const float* __restrict__ bnb, unsigned short* __restrict__ att) {
  const int c = blockIdx.x, d = threadIdx.x;
  float v[Bv];
  float sum = 0.f, sumsq = 0.f;
#pragma unroll
  for (int b = 0; b < Bv; ++b) {
    float e = en[(size_t)b * 4096 + c * 64 + d];
    float m = e;
#pragma unroll
    for (int o = 32; o > 0; o >>= 1) m = fmaxf(m, __shfl_xor(m, o));
    v[b] = m - e;
    sum += v[b]; sumsq += v[b] * v[b];
  }
#pragma unroll
  for (int o = 32; o > 0; o >>= 1) { sum += __shfl_xor(sum, o); sumsq += __shfl_xor(sumsq, o); }
  const float inv = 1.f / (float)(Bv * Cv);
  float mu = sum * inv;
  float var = sumsq * inv - mu * mu;
  float rs = rsqrtf(var + 1e-5f);
  float g = bng[c], be = bnb[c];
#pragma unroll
  for (int b = 0; b < Bv; ++b)
    att[(size_t)b * 4096 + c * 64 + d] = f2b(g * (v[b] - mu) * rs + be);
}

// ---------------------------------------------------------------------------
// dynmega: R5 structure; this round's ONLY lever = VALU reduction:
//  (1) sigmoid via v_rcp, (2) v_cvt bf16 packs, (3) chunk loop unrolled x2
//  so LDS buffer bases are compile-time per half.
// ---------------------------------------------------------------------------
__global__ __launch_bounds__(256)
void dynmega_kernel(const unsigned short* __restrict__ xbT,
                    const unsigned short* __restrict__ x1b,
                    const unsigned short* __restrict__ attB,
                    const unsigned short* __restrict__ WcmB,
                    const unsigned short* __restrict__ WdwB,
                    const float* __restrict__ x, const float* __restrict__ bcm,
                    const float* __restrict__ bdw, const float* __restrict__ gamma_p,
                    float* __restrict__ dout) {
  __shared__ __align__(16) unsigned short XG[64 * 72];
  __shared__ __align__(16) char buf[32768];  // 2 x 16KB {WT 8KB, X1 8KB}
  __shared__ __align__(16) unsigned short SBt[4 * 16 * 72];
  const int tid = threadIdx.x, wave = tid >> 6, lane = tid & 63;
  const int m0 = blockIdx.x * 64, b = blockIdx.y;
  // ---- head: xglb tile -> XG ----
  {
    unsigned short* XB = (unsigned short*)buf;
    float* Xr = (float*)(buf + 8192);
    stage_tile(&xbT[((size_t)b * 1024 + m0) * 64], 64, XB, wave, lane);
    {
      int o = tid >> 2, ms = (tid & 3) * 16;
      const float* xs = &x[((size_t)(b * 64 + o) << 10) + m0 + ms];
#pragma unroll
      for (int q = 0; q < 4; ++q)
        *reinterpret_cast<f32x4*>(&Xr[o * 68 + ms + q * 4]) =
            *reinterpret_cast<const f32x4*>(xs + q * 4);
    }
    __syncthreads();
    bf16x8 afA[2];
#pragma unroll
    for (int ks = 0; ks < 2; ++ks)
      afA[ks] = *reinterpret_cast<const bf16x8*>(
          &attB[(size_t)b * 4096 + (wave * 16 + (lane & 15)) * 64 + ks * 32 + (lane >> 4) * 8]);
    const float g0 = gamma_p[0];
#pragma unroll
    for (int j = 0; j < 4; ++j) {
      f32x4 ah = (f32x4){0.f, 0.f, 0.f, 0.f};
#pragma unroll
      for (int ks = 0; ks < 2; ++ks) {
        bf16x8 bfh = fragr(XB, j * 16 + (lane & 15), ks, lane);
        ah = __builtin_amdgcn_mfma_f32_16x16x32_bf16(afA[ks], bfh, ah, 0, 0, 0);
      }
      us4 gv;
#pragma unroll
      for (int r = 0; r < 4; ++r)
        gv[r] =
            f2bh(g0 * ah[r] + Xr[(wave * 16 + (lane >> 4) * 4 + r) * 68 + j * 16 + (lane & 15)]);
      *reinterpret_cast<us4*>(
          &XG[(j * 16 + (lane & 15)) * 72 + wave * 16 + (lane >> 4) * 4]) = gv;
    }
  }
  __syncthreads();  // XG ready; buf reusable
  bf16x8 xgf[2];
#pragma unroll
  for (int ks = 0; ks < 2; ++ks)
    xgf[ks] = *reinterpret_cast<const bf16x8*>(
        &XG[(wave * 16 + (lane & 15)) * 72 + ks * 32 + (lane >> 4) * 8]);
  stage_tile(&WcmB[0], 64, (unsigned short*)buf, wave, lane);
  stage_tile(&x1b[(size_t)b * 65536], 1024, (unsigned short*)(buf + 8192), wave, lane);
  __syncthreads();
  f32x4 accy[4];
#pragma unroll
  for (int j = 0; j < 4; ++j) accy[j] = (f32x4){0.f, 0.f, 0.f, 0.f};
  unsigned short* SB = &SBt[wave * 16 * 72];

  // one chunk's compute against buffer at compile-time offset CURBASE
  auto chunk_body = [&](const char* base, int ch) {
    const unsigned short* WTcur = (const unsigned short*)base;
    const unsigned short* X1cur = (const unsigned short*)(base + 8192);
#pragma unroll
    for (int i = 0; i < 4; ++i) {
      f32x4 s = (f32x4){0.f, 0.f, 0.f, 0.f};
#pragma unroll
      for (int ks = 0; ks < 2; ++ks) {
        bf16x8 af = fragr(WTcur, i * 16 + (lane & 15), ks, lane);
        s = __builtin_amdgcn_mfma_f32_16x16x32_bf16(af, xgf[ks], s, 0, 0, 0);
      }
      f32x4 bc4 = *reinterpret_cast<const f32x4*>(&bcm[ch * 64 + i * 16 + (lane >> 4) * 4]);
      us4 sv;
#pragma unroll
      for (int r = 0; r < 4; ++r) sv[r] = f2bh(sigmoidf_(s[r] + bc4[r]));
      *reinterpret_cast<us4*>(&SB[(lane & 15) * 72 + i * 16 + (lane >> 4) * 4]) = sv;
    }
#pragma unroll
    for (int ks = 0; ks < 2; ++ks) {
      bf16x8 b2 = *reinterpret_cast<const bf16x8*>(
          &SB[(lane & 15) * 72 + ks * 32 + (lane >> 4) * 8]);
#pragma unroll
      for (int jc = 0; jc < 4; ++jc) {
        bf16x8 a2 = fragr(X1cur, jc * 16 + (lane & 15), ks, lane);
        accy[jc] = __builtin_amdgcn_mfma_f32_16x16x32_bf16(a2, b2, accy[jc], 0, 0, 0);
      }
    }
  };

  for (int hp = 0; hp < 8; ++hp) {
    {  // ch = 2*hp, slot 0; prefetch ch+1 -> slot 1
      const int ch = hp * 2;
      stage_tile(&WcmB[(size_t)(ch + 1) * 4096], 64, (unsigned short*)(buf + 16384), wave, lane);
      stage_tile(&x1b[(size_t)b * 65536 + (ch + 1) * 64], 1024,
                 (unsigned short*)(buf + 16384 + 8192), wave, lane);
      chunk_body(buf, ch);
      __syncthreads();
    }
    {  // ch = 2*hp+1, slot 1; prefetch ch+1 -> slot 0 (if exists)
      const int ch = hp * 2 + 1;
      if (hp < 7) {
        stage_tile(&WcmB[(size_t)(ch + 1) * 4096], 64, (unsigned short*)buf, wave, lane);
        stage_tile(&x1b[(size_t)b * 65536 + (ch + 1) * 64], 1024,
                   (unsigned short*)(buf + 8192), wave, lane);
      }
      chunk_body(buf + 16384, ch);
      __syncthreads();
    }
  }
  // epilogue (wave-private SB reuse): y1 = lrelu(accy) -> YT; out = lrelu(Wdw@y1+bdw)
  unsigned short* YT = SB;
#pragma unroll
  for (int jc = 0; jc < 4; ++jc) {
    us4 yv;
#pragma unroll
    for (int r = 0; r < 4; ++r) yv[r] = f2bh(lrelu(accy[jc][r]));
    *reinterpret_cast<us4*>(&YT[(lane & 15) * 72 + jc * 16 + (lane >> 4) * 4]) = yv;
  }
  bf16x8 afW[4][2];
#pragma unroll
  for (int jo = 0; jo < 4; ++jo)
#pragma unroll
    for (int ks = 0; ks < 2; ++ks)
      afW[jo][ks] = *reinterpret_cast<const bf16x8*>(
          &WdwB[(jo * 16 + (lane & 15)) * 64 + ks * 32 + (lane >> 4) * 8]);
  f32x4 accf[4];
#pragma unroll
  for (int j = 0; j < 4; ++j) accf[j] = (f32x4){0.f, 0.f, 0.f, 0.f};
#pragma unroll
  for (int ks = 0; ks < 2; ++ks) {
    bf16x8 yf = *reinterpret_cast<const bf16x8*>(
        &YT[(lane & 15) * 72 + ks * 32 + (lane >> 4) * 8]);
#pragma unroll
    for (int jo = 0; jo < 4; ++jo)
      accf[jo] = __builtin_amdgcn_mfma_f32_16x16x32_bf16(afW[jo][ks], yf, accf[jo], 0, 0, 0);
  }
#pragma unroll
  for (int jo = 0; jo < 4; ++jo) {
    f32x4 bs4 = *reinterpret_cast<const f32x4*>(&bdw[jo * 16 + (lane >> 4) * 4]);
#pragma unroll
    for (int r = 0; r < 4; ++r) {
      int o = jo * 16 + (lane >> 4) * 4 + r;
      dout[((size_t)(b * 64 + o) << 10) + m0 + wave * 16 + (lane & 15)] =
          lrelu(accf[jo][r] + bs4[r]);
    }
  }
}

extern "C" void kernel_launch(void* const* d_in, const int* in_sizes, int n_in,
                              void* d_out, int out_size, void* d_ws, size_t ws_size,
                              hipStream_t stream) {
  const float* x     = (const float*)d_in[0];
  const float* W_sa  = (const float*)d_in[1];
  const float* W_sw  = (const float*)d_in[2];
  const float* b_sw  = (const float*)d_in[3];
  const float* bn_g  = (const float*)d_in[4];
  const float* bn_b  = (const float*)d_in[5];
  const float* gamma = (const float*)d_in[6];
  const float* W_cm  = (const float*)d_in[7];
  const float* b_cm  = (const float*)d_in[8];
  const float* W_dw  = (const float*)d_in[9];
  const float* b_dw  = (const float*)d_in[10];
  float* out = (float*)d_out;

  char* ws = (char*)d_ws;
  const size_t MB = 1024 * 1024;
  unsigned short* xb     = (unsigned short*)(ws + 0 * MB);    // 4MB
  unsigned short* xbT    = (unsigned short*)(ws + 4 * MB);    // 4MB
  unsigned short* WsaB   = (unsigned short*)(ws + 8 * MB);    // 2MB
  unsigned short* WcmB   = (unsigned short*)(ws + 10 * MB);   // 128KB
  unsigned short* WswB   = (unsigned short*)(ws + 10 * MB + 256 * 1024);  // 8KB
  unsigned short* WdwB   = (unsigned short*)(ws + 10 * MB + 288 * 1024);  // 8KB
  unsigned short* x1b    = (unsigned short*)(ws + 11 * MB);   // 4MB
  float*          en     = (float*)(ws + 15 * MB);            // 512KB
  unsigned short* attB   = (unsigned short*)(ws + 16 * MB);   // 256KB

  prep_kernel<<<2084, 256, 0, stream>>>(x, W_sa, W_cm, W_sw, W_dw, xb, xbT, WsaB, WcmB, WswB,
                                        WdwB);
  k1x1_kernel<<<dim3(16, Bv), 256, 0, stream>>>(xb, WsaB, WswB, x, b_sw, x1b, en);
  bn_att_kernel<<<Cv, 64, 0, stream>>>(en, bn_g, bn_b, attB);
  dynmega_kernel<<<dim3(16, Bv), 256, 0, stream>>>(xbT, x1b, attB, WcmB, WdwB, x, b_cm, b_dw,
                                                   gamma, out);
}